// Round 2
// baseline (558.653 us; speedup 1.0000x reference)
//
#include <hip/hip_runtime.h>

#define NEG_INF (-3.402823466e+38f)  // -FLT_MAX

// Branchless insert of 16 window-sums into sorted top-12.
// KLO/KHI: which of the 16 elements produce a valid (inserted) window.
template <int KLO, int KHI>
__device__ __forceinline__ void proc16(const float* __restrict__ p,
                                       float h[4], float& w, float L[12]) {
    float xs[16];
    float4 a = *(const float4*)(p + 0);
    float4 b = *(const float4*)(p + 4);
    float4 c = *(const float4*)(p + 8);
    float4 d = *(const float4*)(p + 12);
    xs[0] = a.x;  xs[1] = a.y;  xs[2] = a.z;  xs[3] = a.w;
    xs[4] = b.x;  xs[5] = b.y;  xs[6] = b.z;  xs[7] = b.w;
    xs[8] = c.x;  xs[9] = c.y;  xs[10] = c.z; xs[11] = c.w;
    xs[12] = d.x; xs[13] = d.y; xs[14] = d.z; xs[15] = d.w;
#pragma unroll
    for (int k = 0; k < 16; ++k) {
        float xv = xs[k];
        w += xv - h[k & 3];   // running 4-window sum (= 4*wmean; /4 folded into epilogue)
        h[k & 3] = xv;        // static index after unroll
        if (k >= KLO && k < KHI) {
            float run = w;
#pragma unroll
            for (int j = 0; j < 12; ++j) {
                float hi = fmaxf(L[j], run);
                run = fminf(L[j], run);
                L[j] = hi;
            }
        }
    }
}

// One block = 256 threads = 256 rows = exactly 2 output entries (F=128).
// Phase = 64 floats per row (256 B contiguous bursts). Per load instruction a
// wave covers 4 rows x 256 B (vs 16 rows x 64 B before) for DRAM page locality.
__global__ __launch_bounds__(256, 2) void ssrp_kernel(const float* __restrict__ x,
                                                      float* __restrict__ out) {
    __shared__ float tile[256 * 68];  // stride 68 floats: 16B-aligned, balanced banks
    __shared__ float wsum[4];

    const int t = threadIdx.x;
    const int wv = t >> 6;       // wave 0..3
    const int l = t & 63;        // lane
    const int rsub = l >> 4;     // 0..3  row-within-load-instruction
    const int cq = l & 15;       // 0..15 float4 col within 64-float phase chunk

    const long long rowBase = (long long)blockIdx.x * 256;
    const float4* __restrict__ x4 = (const float4*)x;
    // this lane's base row: rows r_i = (wv*64 + rsub) + 4*i, i = 0..15
    const float4* __restrict__ bp = x4 + (rowBase + (wv << 6) + rsub) * 250;
    const int ldsBase = ((wv << 6) + rsub) * 68 + (cq << 2);  // floats

    // prefetch phase 0 (cols 0..15, all valid)
    float4 pf[16];
#pragma unroll
    for (int i = 0; i < 16; ++i) pf[i] = bp[i * 1000 + cq];

    float L[12];
#pragma unroll
    for (int j = 0; j < 12; ++j) L[j] = NEG_INF;
    float h[4] = {0.f, 0.f, 0.f, 0.f};
    float w = 0.f;

    for (int s = 0; s < 16; ++s) {
        // write prefetched phase to LDS: row (wv*64 + 4i + rsub), float4-col cq
#pragma unroll
        for (int i = 0; i < 16; ++i)
            *(float4*)(&tile[ldsBase + i * (4 * 68)]) = pf[i];

        // issue prefetch for next phase (overlaps this phase's compute)
        if (s + 1 < 15) {
            const int col = (s + 1) * 16 + cq;
#pragma unroll
            for (int i = 0; i < 16; ++i) pf[i] = bp[i * 1000 + col];
        } else if (s + 1 == 15) {
            const int col = 240 + cq;       // valid float4 cols are < 250
            const bool ok = col < 250;
            const float4 z = make_float4(0.f, 0.f, 0.f, 0.f);
#pragma unroll
            for (int i = 0; i < 16; ++i) pf[i] = ok ? bp[i * 1000 + col] : z;
        }
        __syncthreads();

        const float* p = tile + t * 68;
        if (s == 0) {
            proc16<3, 16>(p, h, w, L);       // first window completes at element 3
            proc16<0, 16>(p + 16, h, w, L);
            proc16<0, 16>(p + 32, h, w, L);
            proc16<0, 16>(p + 48, h, w, L);
        } else if (s == 15) {
            proc16<0, 16>(p, h, w, L);       // elements 960..975
            proc16<0, 16>(p + 16, h, w, L);  // 976..991
            proc16<0, 8>(p + 32, h, w, L);   // 992..999 valid; 1000.. is zero-pad
            // elements 1008..1023 skipped entirely
        } else {
            proc16<0, 16>(p, h, w, L);
            proc16<0, 16>(p + 16, h, w, L);
            proc16<0, 16>(p + 32, h, w, L);
            proc16<0, 16>(p + 48, h, w, L);
        }
        __syncthreads();
    }

    // sum of top-12 window sums for this row
    float s12 = 0.f;
#pragma unroll
    for (int j = 0; j < 12; ++j) s12 += L[j];

    // wave reduce (all 64 rows of a wave belong to the same output entry group)
#pragma unroll
    for (int off = 1; off < 64; off <<= 1) s12 += __shfl_xor(s12, off, 64);

    if ((t & 63) == 0) wsum[t >> 6] = s12;
    __syncthreads();

    // out = sum(rows) / (W=4 * K=12 * F=128); each output written exactly once
    if (t == 0) out[blockIdx.x * 2 + 0] = (wsum[0] + wsum[1]) * (1.0f / 6144.0f);
    if (t == 128) out[blockIdx.x * 2 + 1] = (wsum[2] + wsum[3]) * (1.0f / 6144.0f);
}

extern "C" void kernel_launch(void* const* d_in, const int* in_sizes, int n_in,
                              void* d_out, int out_size, void* d_ws, size_t ws_size,
                              hipStream_t stream) {
    const float* x = (const float*)d_in[0];
    float* out = (float*)d_out;
    const long long total = (long long)in_sizes[0];  // 16*128*128*1000
    const int rows = (int)(total / 1000);            // 262144
    const int blocks = rows / 256;                   // 1024 (= out_size/2)
    hipLaunchKernelGGL(ssrp_kernel, dim3(blocks), dim3(256), 0, stream, x, out);
}

// Round 3
// 289.590 us; speedup vs baseline: 1.9291x; 1.9291x over previous
//
#include <hip/hip_runtime.h>

#define NEG_INF (-3.402823466e+38f)  // -FLT_MAX

// One iteration: lane holds 4 consecutive elements (float4 a) of the row chunk
// [256*it, 256*it+256). Computes the 4 window-4 sums ending at those elements.
// cy/cz/cw carry lane 63's a.y/a.z/a.w to the next iteration (used by lane 0).
__device__ __forceinline__ void win4(const float4 a, const int l, const int prevlane,
                                     float& cy, float& cz, float& cw,
                                     float& w0, float& w1, float& w2, float& w3) {
    // previous 3 elements = lane (l-1)'s a.y, a.z, a.w (wraps to lane 63)
    float sy = __shfl(a.y, prevlane, 64);
    float sz = __shfl(a.z, prevlane, 64);
    float sw = __shfl(a.w, prevlane, 64);
    float p1 = (l == 0) ? cw : sw;  // e-1
    float p2 = (l == 0) ? cz : sz;  // e-2
    float p3 = (l == 0) ? cy : sy;  // e-3
    w0 = a.x + p1 + p2 + p3;
    w1 = w0 + a.y - p3;
    w2 = w1 + a.z - p2;
    w3 = w2 + a.w - p1;
    // lane 0's shuffled values ARE lane 63's current-chunk values -> carry
    cy = sy; cz = sz; cw = sw;
}

// Block = 4 waves; wave = 1 row at a time, 32 consecutive rows; block covers
// 128 rows = exactly one output element. Register-only: no LDS tiles, no
// hot-loop barriers, perfectly coalesced 1 KB/instruction row streaming.
__global__ __launch_bounds__(256) void ssrp_wave_kernel(const float* __restrict__ x,
                                                        float* __restrict__ out) {
    __shared__ float wsum[4];
    const int t = threadIdx.x;
    const int wv = t >> 6;
    const int l = t & 63;
    const int prevlane = (l + 63) & 63;

    const long long rowBase = (long long)blockIdx.x * 128 + (long long)wv * 32;
    const float4* __restrict__ x4 = (const float4*)x;
    const float4* rowp = x4 + rowBase * 250;

    // iter-3 float4 column, clamped (valid cols < 250; lanes 58..63 masked anyway)
    const int c3 = (192 + l <= 249) ? (192 + l) : 249;

    // prefetch row 0
    float4 n0 = rowp[l];
    float4 n1 = rowp[64 + l];
    float4 n2 = rowp[128 + l];
    float4 n3 = rowp[c3];

    float acc = 0.f;

    for (int r = 0; r < 32; ++r) {
        // next-row pointer (last iteration reloads current row; values unused)
        const float4* rp2 = (r + 1 < 32) ? (rowp + 250) : rowp;

        float v[16];
        float cy = 0.f, cz = 0.f, cw = 0.f;
        float w0, w1, w2, w3;

        // iter 0: elements 0..255; windows at e=0,1,2 invalid (lane 0 only).
        // With carry=0, lane0's w3 = x0+x1+x2+x3 is exact.
        win4(n0, l, prevlane, cy, cz, cw, w0, w1, w2, w3);
        {
            const bool inv = (l == 0);
            v[0] = inv ? NEG_INF : w0;
            v[1] = inv ? NEG_INF : w1;
            v[2] = inv ? NEG_INF : w2;
            v[3] = w3;
        }
        n0 = rp2[l];  // prefetch next row chunk 0 (hides under remaining compute)

        // iter 1: elements 256..511
        win4(n1, l, prevlane, cy, cz, cw, w0, w1, w2, w3);
        v[4] = w0; v[5] = w1; v[6] = w2; v[7] = w3;
        n1 = rp2[64 + l];

        // iter 2: elements 512..767
        win4(n2, l, prevlane, cy, cz, cw, w0, w1, w2, w3);
        v[8] = w0; v[9] = w1; v[10] = w2; v[11] = w3;
        n2 = rp2[128 + l];

        // iter 3: elements 768..999; windows valid only for lanes 0..57
        win4(n3, l, prevlane, cy, cz, cw, w0, w1, w2, w3);
        {
            const bool inv = (l >= 58);
            v[12] = inv ? NEG_INF : w0;
            v[13] = inv ? NEG_INF : w1;
            v[14] = inv ? NEG_INF : w2;
            v[15] = inv ? NEG_INF : w3;
        }
        n3 = rp2[c3];

        // ---- per-lane bitonic sort-16, descending (static indices -> registers)
#pragma unroll
        for (int k = 2; k <= 16; k <<= 1) {
#pragma unroll
            for (int j = k >> 1; j > 0; j >>= 1) {
#pragma unroll
                for (int i = 0; i < 16; ++i) {
                    const int ix = i ^ j;
                    if (ix > i) {
                        const bool up = ((i & k) == 0);
                        const float a = v[i], b = v[ix];
                        const float mx = fmaxf(a, b), mn = fminf(a, b);
                        v[i] = up ? mx : mn;
                        v[ix] = up ? mn : mx;
                    }
                }
            }
        }

        // ---- extract global top-12 across the wave (997 valid candidates >= 12)
        float s12 = 0.f;
#pragma unroll
        for (int rd = 0; rd < 12; ++rd) {
            float g = v[0];
#pragma unroll
            for (int off = 32; off >= 1; off >>= 1)
                g = fmaxf(g, __shfl_xor(g, off, 64));
            s12 += g;  // uniform across lanes
            const unsigned long long ball = __ballot(v[0] == g);
            const bool pop = (l == (int)__builtin_ctzll(ball));  // unique winner on ties
#pragma unroll
            for (int i = 0; i < 11; ++i) v[i] = pop ? v[i + 1] : v[i];
            // a lane pops at most 12 times -> only its top-12 entries are ever read
        }
        acc += s12;

        rowp = rp2;
    }

    if (l == 0) wsum[wv] = acc;
    __syncthreads();
    // out = sum over 128 rows of top12-sum / (W=4 * K=12 * F=128)
    if (t == 0)
        out[blockIdx.x] = (wsum[0] + wsum[1] + wsum[2] + wsum[3]) * (1.0f / 6144.0f);
}

extern "C" void kernel_launch(void* const* d_in, const int* in_sizes, int n_in,
                              void* d_out, int out_size, void* d_ws, size_t ws_size,
                              hipStream_t stream) {
    const float* x = (const float*)d_in[0];
    float* out = (float*)d_out;
    const long long total = (long long)in_sizes[0];  // 16*128*128*1000
    const int rows = (int)(total / 1000);            // 262144
    const int blocks = rows / 128;                   // 2048 == out_size
    hipLaunchKernelGGL(ssrp_wave_kernel, dim3(blocks), dim3(256), 0, stream, x, out);
}

// Round 4
// 262.694 us; speedup vs baseline: 2.1266x; 1.1024x over previous
//
#include <hip/hip_runtime.h>

#define NEG_INF (-3.402823466e+38f)  // -FLT_MAX

// max with DPP row-rotate (pure VALU pipe, no DS). CTRL: 0x121=ror:1 .. 0x128=ror:8
template <int CTRL>
__device__ __forceinline__ float rormax(float v) {
    int sh = __builtin_amdgcn_update_dpp(__float_as_int(v), __float_as_int(v),
                                         CTRL, 0xF, 0xF, false);
    return fmaxf(v, __int_as_float(sh));
}

// all-lanes wave max: 4 DPP rotations (within 16) + 2 cross-group shuffles
__device__ __forceinline__ float wave_max_all(float g) {
    g = rormax<0x121>(g);   // ror:1
    g = rormax<0x122>(g);   // ror:2
    g = rormax<0x124>(g);   // ror:4
    g = rormax<0x128>(g);   // ror:8  -> row(16) max in all lanes
    g = fmaxf(g, __shfl_xor(g, 16, 64));
    g = fmaxf(g, __shfl_xor(g, 32, 64));
    return g;
}

// One iteration: lane holds 4 consecutive elements (float4 a) of the row chunk.
// Computes the 4 window-4 sums ending at those elements.
__device__ __forceinline__ void win4(const float4 a, const int l, const int prevlane,
                                     float& cy, float& cz, float& cw,
                                     float& w0, float& w1, float& w2, float& w3) {
    float sy = __shfl(a.y, prevlane, 64);
    float sz = __shfl(a.z, prevlane, 64);
    float sw = __shfl(a.w, prevlane, 64);
    float p1 = (l == 0) ? cw : sw;  // e-1
    float p2 = (l == 0) ? cz : sz;  // e-2
    float p3 = (l == 0) ? cy : sy;  // e-3
    w0 = a.x + p1 + p2 + p3;
    w1 = w0 + a.y - p3;
    w2 = w1 + a.z - p2;
    w3 = w2 + a.w - p1;
    cy = sy; cz = sz; cw = sw;
}

// Block = 4 waves; wave = 1 row at a time, 32 consecutive rows; block covers
// 128 rows = exactly one output element. Register-only row streaming.
__global__ __launch_bounds__(256) void ssrp_wave_kernel(const float* __restrict__ x,
                                                        float* __restrict__ out) {
    __shared__ float wsum[4];
    const int t = threadIdx.x;
    const int wv = t >> 6;
    const int l = t & 63;
    const int prevlane = (l + 63) & 63;

    const long long rowBase = (long long)blockIdx.x * 128 + (long long)wv * 32;
    const float4* __restrict__ x4 = (const float4*)x;
    const float4* rowp = x4 + rowBase * 250;

    const int c3 = (192 + l <= 249) ? (192 + l) : 249;  // iter-3 col, clamped

    // prefetch row 0
    float4 n0 = rowp[l];
    float4 n1 = rowp[64 + l];
    float4 n2 = rowp[128 + l];
    float4 n3 = rowp[c3];

    float acc = 0.f;

#pragma unroll 1
    for (int r = 0; r < 32; ++r) {
        const float4* rp2 = (r + 1 < 32) ? (rowp + 250) : rowp;

        float v[16];
        float cy = 0.f, cz = 0.f, cw = 0.f;
        float w0, w1, w2, w3;

        // iter 0: elements 0..255; windows at e=0,1,2 invalid (lane 0 only)
        win4(n0, l, prevlane, cy, cz, cw, w0, w1, w2, w3);
        {
            const bool inv = (l == 0);
            v[0] = inv ? NEG_INF : w0;
            v[1] = inv ? NEG_INF : w1;
            v[2] = inv ? NEG_INF : w2;
            v[3] = w3;
        }
        n0 = rp2[l];  // prefetch next row (overlaps this row's compute)

        win4(n1, l, prevlane, cy, cz, cw, w0, w1, w2, w3);
        v[4] = w0; v[5] = w1; v[6] = w2; v[7] = w3;
        n1 = rp2[64 + l];

        win4(n2, l, prevlane, cy, cz, cw, w0, w1, w2, w3);
        v[8] = w0; v[9] = w1; v[10] = w2; v[11] = w3;
        n2 = rp2[128 + l];

        // iter 3: elements 768..999; windows valid only for lanes 0..57
        win4(n3, l, prevlane, cy, cz, cw, w0, w1, w2, w3);
        {
            const bool inv = (l >= 58);
            v[12] = inv ? NEG_INF : w0;
            v[13] = inv ? NEG_INF : w1;
            v[14] = inv ? NEG_INF : w2;
            v[15] = inv ? NEG_INF : w3;
        }
        n3 = rp2[c3];

        // ---- per-lane bitonic sort-16, descending (static indices -> registers)
#pragma unroll
        for (int k = 2; k <= 16; k <<= 1) {
#pragma unroll
            for (int j = k >> 1; j > 0; j >>= 1) {
#pragma unroll
                for (int i = 0; i < 16; ++i) {
                    const int ix = i ^ j;
                    if (ix > i) {
                        const bool up = ((i & k) == 0);
                        const float a = v[i], b = v[ix];
                        const float mx = fmaxf(a, b), mn = fminf(a, b);
                        v[i] = up ? mx : mn;
                        v[ix] = up ? mn : mx;
                    }
                }
            }
        }

        // ---- extract global top-12 across the wave (DPP-based max reduce)
        float s12 = 0.f;
#pragma unroll
        for (int rd = 0; rd < 12; ++rd) {
            const float g = wave_max_all(v[0]);
            s12 += g;  // uniform across lanes
            const unsigned long long ball = __ballot(v[0] == g);
            const bool pop = (l == (int)__builtin_ctzll(ball));  // unique winner on ties
#pragma unroll
            for (int i = 0; i < 11; ++i) v[i] = pop ? v[i + 1] : v[i];
        }
        acc += s12;

        rowp = rp2;
    }

    if (l == 0) wsum[wv] = acc;
    __syncthreads();
    // out = sum over 128 rows of top12-sum / (W=4 * K=12 * F=128)
    if (t == 0)
        out[blockIdx.x] = (wsum[0] + wsum[1] + wsum[2] + wsum[3]) * (1.0f / 6144.0f);
}

extern "C" void kernel_launch(void* const* d_in, const int* in_sizes, int n_in,
                              void* d_out, int out_size, void* d_ws, size_t ws_size,
                              hipStream_t stream) {
    const float* x = (const float*)d_in[0];
    float* out = (float*)d_out;
    const long long total = (long long)in_sizes[0];  // 16*128*128*1000
    const int rows = (int)(total / 1000);            // 262144
    const int blocks = rows / 128;                   // 2048 == out_size
    hipLaunchKernelGGL(ssrp_wave_kernel, dim3(blocks), dim3(256), 0, stream, x, out);
}